// Round 4
// baseline (173.677 us; speedup 1.0000x reference)
//
#include <hip/hip_runtime.h>
#include <stdint.h>

#define TOKENS  256
#define INF     4096
#define OUTF    11008
#define NGROUPS 32
#define KSPLIT  2
#define PHK     128                       // K per phase = one quant group
#define NPH     ((INF / KSPLIT) / PHK)    // 16 phases per block
#define NTH     256

typedef __attribute__((ext_vector_type(2))) _Float16 f16x2;
typedef __attribute__((ext_vector_type(8))) _Float16 f16x8;
typedef __attribute__((ext_vector_type(2))) __fp16   pkh2;
typedef __attribute__((ext_vector_type(4))) float    f32x4;

union U32H2 { uint32_t u; f16x2 h; };
union H8    { f16x2 h2[4]; f16x8 h8; };
union PK    { pkh2 p; f16x2 h; };

// ---------------- pre-kernel: fused {x fp32->fp16 permuted} + {out <- bias} --
__global__ __launch_bounds__(NTH)
void prep(const float* __restrict__ x, _Float16* __restrict__ x16,
          const float* __restrict__ bias, float* __restrict__ out) {
    const int b = blockIdx.x;
    if (b < 512) {
        const int t   = b * NTH + threadIdx.x;        // 0 .. 131071
        const int row = t >> 9;
        const int c   = t & 511;
        const float* p = x + (size_t)row * INF + c * 8;
        f32x4 v0 = *(const f32x4*)p;
        f32x4 v1 = *(const f32x4*)(p + 4);
        H8 o; PK k0, k1, k2, k3;
        k0.p = __builtin_amdgcn_cvt_pkrtz(v0[0], v1[0]);
        k1.p = __builtin_amdgcn_cvt_pkrtz(v0[1], v1[1]);
        k2.p = __builtin_amdgcn_cvt_pkrtz(v0[2], v1[2]);
        k3.p = __builtin_amdgcn_cvt_pkrtz(v0[3], v1[3]);
        o.h2[0] = k0.h; o.h2[1] = k1.h; o.h2[2] = k2.h; o.h2[3] = k3.h;
        *(f16x8*)(x16 + (size_t)row * INF + c * 8) = o.h8;
    } else {
        const int t = (b - 512) * NTH + threadIdx.x;  // 0 .. 704511
        const int c = t % (OUTF / 4);
        const int r = t / (OUTF / 4);
        const f32x4 bv = ((const f32x4*)bias)[c];
        ((f32x4*)out)[(size_t)r * (OUTF / 4) + c] = bv;
    }
}

// ---------------- main kernel: 64x128 tile, K-split x2, NO LDS / NO BARRIER --
// R4 change: R0-R2 all plateaued ~48-52us with every pipe <=35% regardless of
// occupancy (10.8% vs 19.9% -> same time): the per-phase barrier+vmcnt drain
// lockstep was the m233-class structural stall. x16 is 2MB = L2-resident, so
// A-fragments are loaded DIRECTLY from global (same 16B chunks gl2lds staged;
// identical register image) and the whole LDS/barrier/waitcnt machinery is
// deleted. Waves are fully independent dataflow; the block's 4 waves read the
// same A bytes near-in-step -> L1 (per-phase A set = 16KB) absorbs reuse.
// KSPLIT stays 2 (R3 proved KSPLIT=4 atomics blow HBM write traffic 2.2x).
__global__ __launch_bounds__(NTH, 3)
void qlin_main(const _Float16* __restrict__ x16,
               const uint32_t* __restrict__ qweight,
               const uint32_t* __restrict__ qzeros,
               const float* __restrict__ scales,
               float* __restrict__ out)
{
    const int tid = threadIdx.x;

    // ---- XCD-chunked block decode: 86 strips x 8 members over 8 XCDs ----
    // (proven by R1/R2: FETCH_SIZE == 22.5MB == qweight read exactly once)
    const int d  = blockIdx.x;            // HW XCD = d & 7 (round-robin)
    const int cx = d & 7, kk = d >> 3;    // kk in 0..85
    int strip, memb;
    if (kk < 80) { strip = cx * 10 + (kk >> 3); memb = kk & 7; }
    else         { const int t2 = ((kk - 80) << 3) | cx; strip = 80 + (t2 >> 3); memb = t2 & 7; }
    const int bx = strip;                 // 0..85  out-feature block
    const int by = memb >> 1;             // 0..3   token block
    const int ks = memb & 1;              // 0..1   K half

    const int lane = tid & 63;
    const int quad = lane >> 4;
    const int l16  = lane & 15;
    const int wv   = tid >> 6;            // 0..3, wave's 32-col strip

    // ---- A map: direct global loads of the MFMA A-fragments ----
    // af(p, s, mi) = x16[by*64 + mi*16 + l16][ks*2048 + p*128 + s*32 + quad*8 .. +8]
    // (x16 already holds the (j,j+4) pair-permuted layout the f16 MFMA wants.)
    const _Float16* aBase = x16 + (size_t)(by * 64 + l16) * INF
                                + ks * (INF / KSPLIT) + quad * 8;

    // ---- B map ----
    const int col0 = bx * 128 + wv * 32 + l16;   // nf=0 column
    const int col1 = col0 + 16;                  // nf=1 column
    const int bOff0 = quad * OUTF + col0;
    const int bOff1 = quad * OUTF + col1;
    const int zsh   = (col0 & 7) * 4;            // same for col1
    const int qrow0 = ks * (INF / KSPLIT / 8);   // 0 or 256
    const int g0    = ks * (NGROUPS / KSPLIT);   // 0 or 16

    f32x4 acc[4][2];
#pragma unroll
    for (int mi = 0; mi < 4; ++mi)
#pragma unroll
        for (int nf = 0; nf < 2; ++nf)
            acc[mi][nf] = f32x4{0.f, 0.f, 0.f, 0.f};

    uint32_t Breg[2][8];
    float    sS[2][2];
    uint32_t qZ[2][2];

    // ================= prologue: phase 0 B-side prefetch =================
    {
        sS[0][0] = scales[g0 * OUTF + col0];
        sS[0][1] = scales[g0 * OUTF + col1];
        qZ[0][0] = qzeros[g0 * (OUTF / 8) + (col0 >> 3)];
        qZ[0][1] = qzeros[g0 * (OUTF / 8) + (col1 >> 3)];
        const uint32_t* qp = qweight + (size_t)qrow0 * OUTF;
#pragma unroll
        for (int s = 0; s < 4; ++s) {
            Breg[0][2 * s + 0] = qp[(size_t)(s * 4) * OUTF + bOff0];
            Breg[0][2 * s + 1] = qp[(size_t)(s * 4) * OUTF + bOff1];
        }
    }

    // ================= phase loop (ROLLED, 2 phases per iteration) ============
#define PHASE_BODY(PAR, P, DO_PREFETCH)                                          \
    {                                                                            \
        if (DO_PREFETCH) {                                                       \
            const int pn = (P) + 1;                                              \
            const int gn = g0 + pn;                                              \
            sS[1 - (PAR)][0] = scales[gn * OUTF + col0];                         \
            sS[1 - (PAR)][1] = scales[gn * OUTF + col1];                         \
            qZ[1 - (PAR)][0] = qzeros[gn * (OUTF / 8) + (col0 >> 3)];            \
            qZ[1 - (PAR)][1] = qzeros[gn * (OUTF / 8) + (col1 >> 3)];            \
            const uint32_t* qpb = qweight + (size_t)(qrow0 + pn * 16) * OUTF;    \
            _Pragma("unroll")                                                    \
            for (int s = 0; s < 4; ++s) {                                        \
                Breg[1 - (PAR)][2 * s + 0] = qpb[(size_t)(s * 4) * OUTF + bOff0];\
                Breg[1 - (PAR)][2 * s + 1] = qpb[(size_t)(s * 4) * OUTF + bOff1];\
            }                                                                    \
        }                                                                        \
        f16x2 hs2[2], hz2[2];                                                    \
        _Pragma("unroll")                                                        \
        for (int nf = 0; nf < 2; ++nf) {                                         \
            const float s = sS[PAR][nf];                                         \
            const int   z = (int)((qZ[PAR][nf] >> zsh) & 15u) + 1025;            \
            const _Float16 hs = (_Float16)s;                                     \
            const _Float16 hz = (_Float16)(-(float)z);                           \
            hs2[nf] = f16x2{hs, hs};                                             \
            hz2[nf] = f16x2{hz, hz};                                             \
        }                                                                        \
        const _Float16* aP = aBase + (P) * PHK;                                  \
        _Pragma("unroll")                                                        \
        for (int s = 0; s < 4; ++s) {                                            \
            f16x8 af[4];                                                         \
            _Pragma("unroll")                                                    \
            for (int mi = 0; mi < 4; ++mi)                                       \
                af[mi] = *(const f16x8*)(aP + (size_t)mi * (16 * INF) + s * 32); \
            _Pragma("unroll")                                                    \
            for (int nf = 0; nf < 2; ++nf) {                                     \
                const uint32_t q = Breg[PAR][2 * s + nf];                        \
                H8 b;                                                            \
                _Pragma("unroll")                                                \
                for (int j = 0; j < 4; ++j) {                                    \
                    U32H2 u;                                                     \
                    u.u = ((q >> (4 * j)) & 0x000F000Fu) | 0x64006400u;          \
                    b.h2[j] = (u.h + hz2[nf]) * hs2[nf];                         \
                }                                                                \
                __builtin_amdgcn_s_setprio(1);                                   \
                _Pragma("unroll")                                                \
                for (int mi = 0; mi < 4; ++mi)                                   \
                    acc[mi][nf] = __builtin_amdgcn_mfma_f32_16x16x32_f16(        \
                        af[mi], b.h8, acc[mi][nf], 0, 0, 0);                     \
                __builtin_amdgcn_s_setprio(0);                                   \
            }                                                                    \
        }                                                                        \
    }

#pragma unroll 1
    for (int pp = 0; pp < NPH / 2; ++pp) {
        PHASE_BODY(0, 2 * pp, true)
        PHASE_BODY(1, 2 * pp + 1, (pp < NPH / 2 - 1))
    }
#undef PHASE_BODY

    // ================= epilogue: atomic partial accumulate =================
#pragma unroll
    for (int nf = 0; nf < 2; ++nf) {
        const int col = (nf == 0) ? col0 : col1;
#pragma unroll
        for (int mi = 0; mi < 4; ++mi) {
            const int r0 = by * 64 + mi * 16 + quad * 4;
#pragma unroll
            for (int rg = 0; rg < 4; ++rg)
                unsafeAtomicAdd(&out[(size_t)(r0 + rg) * OUTF + col],
                                acc[mi][nf][rg]);
        }
    }
}

// ---------------- fallback (proven R2 kernel) if ws too small ----------------
__global__ __launch_bounds__(NTH, 2)
void qlin_fb(const float* __restrict__ x,
             const uint32_t* __restrict__ qweight,
             const uint32_t* __restrict__ qzeros,
             const float* __restrict__ scales,
             const float* __restrict__ bias,
             float* __restrict__ out)
{
    __shared__ alignas(16) _Float16 Asb[64][40];
    __shared__ alignas(16) _Float16 Bsb[128][40];
    const int tid = threadIdx.x;
    const int bx = blockIdx.x, by = blockIdx.y;
    const int am = tid >> 2, ar = tid & 3;
    const float* xrow = x + (size_t)(by * 64 + am) * INF + ar * 8;
    const int bc = tid & 127, br = tid >> 7;
    const int bn = bx * 128 + bc;
    const int bswz = (bc >> 3) & 3;
    const int lane = tid & 63, quad = lane >> 4, l16 = lane & 15;
    const int wv = tid >> 6, wm = wv >> 1, wn = wv & 1;
    f32x4 acc[2][4];
#pragma unroll
    for (int i = 0; i < 2; ++i)
#pragma unroll
        for (int j = 0; j < 4; ++j) acc[i][j] = f32x4{0.f, 0.f, 0.f, 0.f};
    f32x4 pa0 = *(const f32x4*)(xrow + 0);
    f32x4 pa1 = *(const f32x4*)(xrow + 4);
    uint32_t pq0 = qweight[(size_t)br * OUTF + bn];
    uint32_t pq1 = qweight[(size_t)(br + 2) * OUTF + bn];
    for (int g = 0; g < NGROUPS; ++g) {
        const float s = scales[g * OUTF + bn];
        const uint32_t qzv = qzeros[g * (OUTF / 8) + (bn >> 3)];
        const int z = (int)((qzv >> (4 * (bn & 7))) & 15u) + 1;
        const _Float16 hs = (_Float16)s;
        const _Float16 hz = (_Float16)(-(float)(1024 + z));
        const f16x2 hs2 = {hs, hs}, hz2 = {hz, hz};
#pragma unroll
        for (int t4 = 0; t4 < 4; ++t4) {
            const int it = (g << 2) + t4;
            { H8 ah; PK p0, p1, p2, p3;
              p0.p = __builtin_amdgcn_cvt_pkrtz(pa0[0], pa1[0]);
              p1.p = __builtin_amdgcn_cvt_pkrtz(pa0[1], pa1[1]);
              p2.p = __builtin_amdgcn_cvt_pkrtz(pa0[2], pa1[2]);
              p3.p = __builtin_amdgcn_cvt_pkrtz(pa0[3], pa1[3]);
              ah.h2[0] = p0.h; ah.h2[1] = p1.h; ah.h2[2] = p2.h; ah.h2[3] = p3.h;
              *(f16x8*)&Asb[am][ar * 8] = ah.h8; }
            { const uint32_t qq[2] = {pq0, pq1};
#pragma unroll
              for (int rr = 0; rr < 2; ++rr) {
                  const int r = br + rr * 2; H8 bh;
#pragma unroll
                  for (int jp = 0; jp < 4; ++jp) {
                      U32H2 u; u.u = ((qq[rr] >> (4 * jp)) & 0x000F000Fu) | 0x64006400u;
                      bh.h2[jp] = (u.h + hz2) * hs2;
                  }
                  *(f16x8*)&Bsb[bc][(r ^ bswz) * 8] = bh.h8;
              } }
            __syncthreads();
            const int itn = (it < 127) ? it + 1 : 127;
            pa0 = *(const f32x4*)(xrow + itn * 32);
            pa1 = *(const f32x4*)(xrow + itn * 32 + 4);
            pq0 = qweight[(size_t)(itn * 4 + br) * OUTF + bn];
            pq1 = qweight[(size_t)(itn * 4 + br + 2) * OUTF + bn];
            f16x8 af[2], bf[4];
#pragma unroll
            for (int mi = 0; mi < 2; ++mi)
                af[mi] = *(const f16x8*)&Asb[wm * 32 + mi * 16 + l16][quad * 8];
#pragma unroll
            for (int ni = 0; ni < 4; ++ni) {
                const int c = wn * 64 + ni * 16 + l16;
                bf[ni] = *(const f16x8*)&Bsb[c][(quad ^ ((c >> 3) & 3)) * 8];
            }
#pragma unroll
            for (int mi = 0; mi < 2; ++mi)
#pragma unroll
                for (int ni = 0; ni < 4; ++ni)
                    acc[mi][ni] = __builtin_amdgcn_mfma_f32_16x16x32_f16(
                        af[mi], bf[ni], acc[mi][ni], 0, 0, 0);
            __syncthreads();
        }
    }
#pragma unroll
    for (int ni = 0; ni < 4; ++ni) {
        const int col = bx * 128 + wn * 64 + ni * 16 + l16;
        const float bv = bias[col];
#pragma unroll
        for (int mi = 0; mi < 2; ++mi) {
            const int row0 = by * 64 + wm * 32 + mi * 16 + quad * 4;
#pragma unroll
            for (int rg = 0; rg < 4; ++rg)
                out[(size_t)(row0 + rg) * OUTF + col] = acc[mi][ni][rg] + bv;
        }
    }
}

extern "C" void kernel_launch(void* const* d_in, const int* in_sizes, int n_in,
                              void* d_out, int out_size, void* d_ws, size_t ws_size,
                              hipStream_t stream) {
    const float*    xx = (const float*)d_in[0];
    const uint32_t* qw = (const uint32_t*)d_in[1];
    const uint32_t* qz = (const uint32_t*)d_in[2];
    const float*    sc = (const float*)d_in[3];
    const float*    bs = (const float*)d_in[4];
    float* out = (float*)d_out;

    const size_t x16_bytes = (size_t)TOKENS * INF * sizeof(_Float16);  // 2 MB
    if (ws_size >= x16_bytes) {
        _Float16* x16 = (_Float16*)d_ws;
        prep<<<512 + (TOKENS * OUTF / 4) / NTH, NTH, 0, stream>>>(xx, x16, bs, out);
        qlin_main<<<(OUTF / 128) * (TOKENS / 64) * KSPLIT, NTH, 0, stream>>>(
            x16, qw, qz, sc, out);
    } else {
        dim3 grid(OUTF / 128, TOKENS / 64);
        qlin_fb<<<grid, NTH, 0, stream>>>(xx, qw, qz, sc, bs, out);
    }
}

// Round 5
// 118.693 us; speedup vs baseline: 1.4633x; 1.4633x over previous
//
#include <hip/hip_runtime.h>
#include <stdint.h>

#define TOKENS  256
#define INF     4096
#define OUTF    11008
#define NGROUPS 32
#define KSPLIT  2
#define PHK     128                       // K per phase = one quant group
#define NPH     ((INF / KSPLIT) / PHK)    // 16 phases per block
#define NTH     256

typedef __attribute__((ext_vector_type(2))) _Float16 f16x2;
typedef __attribute__((ext_vector_type(8))) _Float16 f16x8;
typedef __attribute__((ext_vector_type(2))) __fp16   pkh2;
typedef __attribute__((ext_vector_type(4))) float    f32x4;

union U32H2 { uint32_t u; f16x2 h; };
union H8    { f16x2 h2[4]; f16x8 h8; };
union PK    { pkh2 p; f16x2 h; };

__device__ __forceinline__ void gl2lds16(const void* g, void* l) {
    __builtin_amdgcn_global_load_lds(
        (const __attribute__((address_space(1))) uint32_t*)g,
        (__attribute__((address_space(3))) uint32_t*)l, 16, 0, 0);
}

// ---------------- pre-kernel: fused {x fp32->fp16 permuted} + {out <- bias} --
__global__ __launch_bounds__(NTH)
void prep(const float* __restrict__ x, _Float16* __restrict__ x16,
          const float* __restrict__ bias, float* __restrict__ out) {
    const int b = blockIdx.x;
    if (b < 512) {
        const int t   = b * NTH + threadIdx.x;        // 0 .. 131071
        const int row = t >> 9;
        const int c   = t & 511;
        const float* p = x + (size_t)row * INF + c * 8;
        f32x4 v0 = *(const f32x4*)p;
        f32x4 v1 = *(const f32x4*)(p + 4);
        H8 o; PK k0, k1, k2, k3;
        k0.p = __builtin_amdgcn_cvt_pkrtz(v0[0], v1[0]);
        k1.p = __builtin_amdgcn_cvt_pkrtz(v0[1], v1[1]);
        k2.p = __builtin_amdgcn_cvt_pkrtz(v0[2], v1[2]);
        k3.p = __builtin_amdgcn_cvt_pkrtz(v0[3], v1[3]);
        o.h2[0] = k0.h; o.h2[1] = k1.h; o.h2[2] = k2.h; o.h2[3] = k3.h;
        *(f16x8*)(x16 + (size_t)row * INF + c * 8) = o.h8;
    } else {
        const int t = (b - 512) * NTH + threadIdx.x;  // 0 .. 704511
        const int c = t % (OUTF / 4);
        const int r = t / (OUTF / 4);
        const f32x4 bv = ((const f32x4*)bias)[c];
        ((f32x4*)out)[(size_t)r * (OUTF / 4) + c] = bv;
    }
}

// ---------------- main kernel: 64x128 tile, K-split x2, depth-2 B pipeline ---
// R5: R2 structure (proven 47.7us) + ONE change: qweight/scales/qzeros are
// streamed-once cold-HBM, and depth-1 prefetch made every phase wall-time ~ a
// full loaded HBM round trip (~2650cy vs ~600cy of work; occupancy changes
// were no-ops, R0/R1). B-side prefetch now runs 2 PHASES AHEAD in a 4-slot
// ring (compile-time slot idx via 4-phase unroll + peeled tail). A (x16) is
// L2-resident (2MB) and keeps depth-1 gl2lds.
// Phase-top wait: vmcnt(12) = newest B-batch (12 loads) may stay in flight;
// forces gl2lds(P) + B(P) (issued >=1 phase resp >=2 phases ago) landed.
// Last phase uses vmcnt(0). Issue order pinned: [gl2lds][B batch].
__global__ __launch_bounds__(NTH, 3)
void qlin_main(const _Float16* __restrict__ x16,
               const uint32_t* __restrict__ qweight,
               const uint32_t* __restrict__ qzeros,
               const float* __restrict__ scales,
               float* __restrict__ out)
{
    __shared__ alignas(16) _Float16 As[2][64 * PHK];   // 2 x 16KB double buffer

    const int tid = threadIdx.x;

    // ---- XCD-chunked block decode: 86 strips x 8 members over 8 XCDs ----
    // (proven R1/R2: FETCH_SIZE == 22.5MB == qweight read exactly once)
    const int d  = blockIdx.x;            // HW XCD = d & 7 (round-robin)
    const int cx = d & 7, kk = d >> 3;    // kk in 0..85
    int strip, memb;
    if (kk < 80) { strip = cx * 10 + (kk >> 3); memb = kk & 7; }
    else         { const int t2 = ((kk - 80) << 3) | cx; strip = 80 + (t2 >> 3); memb = t2 & 7; }
    const int bx = strip;                 // 0..85  out-feature block
    const int by = memb >> 1;             // 0..3   token block
    const int ks = memb & 1;              // 0..1   K half

    const int lane = tid & 63;
    const int quad = lane >> 4;
    const int l16  = lane & 15;
    const int wv   = tid >> 6;            // 0..3, wave's 32-col strip

    // ---- A fill map (global_load_lds, lane-linear LDS, pre-swizzled source) ----
    const int rowoff = tid >> 4;          // 0..15
    const int chk    = tid & 15;
    const int row0   = by * 64;
    const uint32_t aoff = (uint32_t)((row0 + rowoff) * (INF * 2)
                                     + ks * (INF / KSPLIT) * 2
                                     + ((chk ^ rowoff) & 15) * 16);
    const char* x16b = (const char*)x16;
    _Float16* ldsW = &As[0][0];
    const int ldsSlotBase = wv * 512;     // f16 units; + r*2048 per round; +8192 per buf

    // ---- B map ----
    const int col0 = bx * 128 + wv * 32 + l16;
    const int col1 = col0 + 16;
    const int bOff0 = quad * OUTF + col0;
    const int bOff1 = quad * OUTF + col1;
    const int zsh   = (col0 & 7) * 4;
    const int qrow0 = ks * (INF / KSPLIT / 8);   // 0 or 256
    const int g0    = ks * (NGROUPS / KSPLIT);   // 0 or 16

    f32x4 acc[4][2];
#pragma unroll
    for (int mi = 0; mi < 4; ++mi)
#pragma unroll
        for (int nf = 0; nf < 2; ++nf)
            acc[mi][nf] = f32x4{0.f, 0.f, 0.f, 0.f};

    uint32_t Breg[4][8];     // 4-slot ring, slot = phase & 3
    float    sS[4][2];
    uint32_t qZ[4][2];

    // ---- B batch loader (12 loads: sS x2, qZ x2, Breg x8) ----
#define LOAD_B(SLOT, PN)                                                         \
    {                                                                            \
        const int gn_ = g0 + (PN);                                               \
        sS[SLOT][0] = scales[gn_ * OUTF + col0];                                 \
        sS[SLOT][1] = scales[gn_ * OUTF + col1];                                 \
        qZ[SLOT][0] = qzeros[gn_ * (OUTF / 8) + (col0 >> 3)];                    \
        qZ[SLOT][1] = qzeros[gn_ * (OUTF / 8) + (col1 >> 3)];                    \
        const uint32_t* qpb_ = qweight + (size_t)(qrow0 + (PN) * 16) * OUTF;     \
        _Pragma("unroll")                                                        \
        for (int s_ = 0; s_ < 4; ++s_) {                                         \
            Breg[SLOT][2 * s_ + 0] = qpb_[(size_t)(s_ * 4) * OUTF + bOff0];      \
            Breg[SLOT][2 * s_ + 1] = qpb_[(size_t)(s_ * 4) * OUTF + bOff1];      \
        }                                                                        \
    }

    // ================= prologue: A(0) + B(0) + B(1) (issue only) ==============
#pragma unroll
    for (int r = 0; r < 4; ++r)
        gl2lds16(x16b + aoff + r * 131072, ldsW + r * 2048 + ldsSlotBase);
    __builtin_amdgcn_sched_barrier(0);    // pin: gl2lds oldest
    LOAD_B(0, 0)
    __builtin_amdgcn_sched_barrier(0);
    LOAD_B(1, 1)

    // ================= phase bodies ===========================================
    // PAR = P & 3 (B ring slot); A buf = P & 1. WAIT0: final-phase full drain.
#define PHASE_BODY(PAR, P, DO_A, DO_B, WAIT0)                                    \
    {                                                                            \
        __builtin_amdgcn_sched_barrier(0);                                       \
        if (WAIT0) { asm volatile("s_waitcnt vmcnt(0)" ::: "memory"); }          \
        else       { asm volatile("s_waitcnt vmcnt(12)" ::: "memory"); }         \
        __builtin_amdgcn_s_barrier();                                            \
        __builtin_amdgcn_sched_barrier(0);                                       \
        if (DO_A) {                                                              \
            const uint32_t pb = (uint32_t)(((P) + 1) * (PHK * 2));               \
            _Float16* ldsN = ldsW + (1 - ((PAR) & 1)) * 8192;                    \
            _Pragma("unroll")                                                    \
            for (int r = 0; r < 4; ++r)                                          \
                gl2lds16(x16b + aoff + r * 131072 + pb,                          \
                         ldsN + r * 2048 + ldsSlotBase);                         \
            __builtin_amdgcn_sched_barrier(0);  /* gl2lds before B batch */      \
        }                                                                        \
        if (DO_B) {                                                              \
            LOAD_B(((PAR) + 2) & 3, (P) + 2)                                     \
        }                                                                        \
        f16x2 hs2[2], hz2[2];                                                    \
        _Pragma("unroll")                                                        \
        for (int nf = 0; nf < 2; ++nf) {                                         \
            const float s = sS[PAR][nf];                                         \
            const int   z = (int)((qZ[PAR][nf] >> zsh) & 15u) + 1025;            \
            const _Float16 hs = (_Float16)s;                                     \
            const _Float16 hz = (_Float16)(-(float)z);                           \
            hs2[nf] = f16x2{hs, hs};                                             \
            hz2[nf] = f16x2{hz, hz};                                             \
        }                                                                        \
        const _Float16* buf = ldsW + ((PAR) & 1) * 8192;                         \
        _Pragma("unroll")                                                        \
        for (int s = 0; s < 4; ++s) {                                            \
            f16x8 af[4];                                                         \
            _Pragma("unroll")                                                    \
            for (int mi = 0; mi < 4; ++mi) {                                     \
                const int m  = mi * 16 + l16;                                    \
                const int sc = ((s * 4 + quad) ^ l16) & 15;                      \
                af[mi] = *(const f16x8*)(buf + m * PHK + sc * 8);                \
            }                                                                    \
            _Pragma("unroll")                                                    \
            for (int nf = 0; nf < 2; ++nf) {                                     \
                const uint32_t q = Breg[PAR][2 * s + nf];                        \
                H8 b;                                                            \
                _Pragma("unroll")                                                \
                for (int j = 0; j < 4; ++j) {                                    \
                    U32H2 u;                                                     \
                    u.u = ((q >> (4 * j)) & 0x000F000Fu) | 0x64006400u;          \
                    b.h2[j] = (u.h + hz2[nf]) * hs2[nf];                         \
                }                                                                \
                __builtin_amdgcn_s_setprio(1);                                   \
                _Pragma("unroll")                                                \
                for (int mi = 0; mi < 4; ++mi)                                   \
                    acc[mi][nf] = __builtin_amdgcn_mfma_f32_16x16x32_f16(        \
                        af[mi], b.h8, acc[mi][nf], 0, 0, 0);                     \
                __builtin_amdgcn_s_setprio(0);                                   \
            }                                                                    \
        }                                                                        \
    }

    // phases 0..11 (all interior: full A+B prefetch, vmcnt(12))
#pragma unroll 1
    for (int pp = 0; pp < 3; ++pp) {
        const int pb4 = pp * 4;
        PHASE_BODY(0, pb4 + 0, true, true, false)
        PHASE_BODY(1, pb4 + 1, true, true, false)
        PHASE_BODY(2, pb4 + 2, true, true, false)
        PHASE_BODY(3, pb4 + 3, true, true, false)
    }
    // peeled tail: phases 12..15 with compile-time prefetch cutoffs
    PHASE_BODY(0, 12, true,  true,  false)   // A(13), B(14)
    PHASE_BODY(1, 13, true,  true,  false)   // A(14), B(15)
    PHASE_BODY(2, 14, true,  false, false)   // A(15)
    PHASE_BODY(3, 15, false, false, true)    // drain
#undef PHASE_BODY
#undef LOAD_B

    // ================= epilogue: atomic partial accumulate =================
#pragma unroll
    for (int nf = 0; nf < 2; ++nf) {
        const int col = (nf == 0) ? col0 : col1;
#pragma unroll
        for (int mi = 0; mi < 4; ++mi) {
            const int r0 = by * 64 + mi * 16 + quad * 4;
#pragma unroll
            for (int rg = 0; rg < 4; ++rg)
                unsafeAtomicAdd(&out[(size_t)(r0 + rg) * OUTF + col],
                                acc[mi][nf][rg]);
        }
    }
}

// ---------------- fallback (proven R2 kernel) if ws too small ----------------
__global__ __launch_bounds__(NTH, 2)
void qlin_fb(const float* __restrict__ x,
             const uint32_t* __restrict__ qweight,
             const uint32_t* __restrict__ qzeros,
             const float* __restrict__ scales,
             const float* __restrict__ bias,
             float* __restrict__ out)
{
    __shared__ alignas(16) _Float16 Asb[64][40];
    __shared__ alignas(16) _Float16 Bsb[128][40];
    const int tid = threadIdx.x;
    const int bx = blockIdx.x, by = blockIdx.y;
    const int am = tid >> 2, ar = tid & 3;
    const float* xrow = x + (size_t)(by * 64 + am) * INF + ar * 8;
    const int bc = tid & 127, br = tid >> 7;
    const int bn = bx * 128 + bc;
    const int bswz = (bc >> 3) & 3;
    const int lane = tid & 63, quad = lane >> 4, l16 = lane & 15;
    const int wv = tid >> 6, wm = wv >> 1, wn = wv & 1;
    f32x4 acc[2][4];
#pragma unroll
    for (int i = 0; i < 2; ++i)
#pragma unroll
        for (int j = 0; j < 4; ++j) acc[i][j] = f32x4{0.f, 0.f, 0.f, 0.f};
    f32x4 pa0 = *(const f32x4*)(xrow + 0);
    f32x4 pa1 = *(const f32x4*)(xrow + 4);
    uint32_t pq0 = qweight[(size_t)br * OUTF + bn];
    uint32_t pq1 = qweight[(size_t)(br + 2) * OUTF + bn];
    for (int g = 0; g < NGROUPS; ++g) {
        const float s = scales[g * OUTF + bn];
        const uint32_t qzv = qzeros[g * (OUTF / 8) + (bn >> 3)];
        const int z = (int)((qzv >> (4 * (bn & 7))) & 15u) + 1;
        const _Float16 hs = (_Float16)s;
        const _Float16 hz = (_Float16)(-(float)(1024 + z));
        const f16x2 hs2 = {hs, hs}, hz2 = {hz, hz};
#pragma unroll
        for (int t4 = 0; t4 < 4; ++t4) {
            const int it = (g << 2) + t4;
            { H8 ah; PK p0, p1, p2, p3;
              p0.p = __builtin_amdgcn_cvt_pkrtz(pa0[0], pa1[0]);
              p1.p = __builtin_amdgcn_cvt_pkrtz(pa0[1], pa1[1]);
              p2.p = __builtin_amdgcn_cvt_pkrtz(pa0[2], pa1[2]);
              p3.p = __builtin_amdgcn_cvt_pkrtz(pa0[3], pa1[3]);
              ah.h2[0] = p0.h; ah.h2[1] = p1.h; ah.h2[2] = p2.h; ah.h2[3] = p3.h;
              *(f16x8*)&Asb[am][ar * 8] = ah.h8; }
            { const uint32_t qq[2] = {pq0, pq1};
#pragma unroll
              for (int rr = 0; rr < 2; ++rr) {
                  const int r = br + rr * 2; H8 bh;
#pragma unroll
                  for (int jp = 0; jp < 4; ++jp) {
                      U32H2 u; u.u = ((qq[rr] >> (4 * jp)) & 0x000F000Fu) | 0x64006400u;
                      bh.h2[jp] = (u.h + hz2) * hs2;
                  }
                  *(f16x8*)&Bsb[bc][(r ^ bswz) * 8] = bh.h8;
              } }
            __syncthreads();
            const int itn = (it < 127) ? it + 1 : 127;
            pa0 = *(const f32x4*)(xrow + itn * 32);
            pa1 = *(const f32x4*)(xrow + itn * 32 + 4);
            pq0 = qweight[(size_t)(itn * 4 + br) * OUTF + bn];
            pq1 = qweight[(size_t)(itn * 4 + br + 2) * OUTF + bn];
            f16x8 af[2], bf[4];
#pragma unroll
            for (int mi = 0; mi < 2; ++mi)
                af[mi] = *(const f16x8*)&Asb[wm * 32 + mi * 16 + l16][quad * 8];
#pragma unroll
            for (int ni = 0; ni < 4; ++ni) {
                const int c = wn * 64 + ni * 16 + l16;
                bf[ni] = *(const f16x8*)&Bsb[c][(quad ^ ((c >> 3) & 3)) * 8];
            }
#pragma unroll
            for (int mi = 0; mi < 2; ++mi)
#pragma unroll
                for (int ni = 0; ni < 4; ++ni)
                    acc[mi][ni] = __builtin_amdgcn_mfma_f32_16x16x32_f16(
                        af[mi], bf[ni], acc[mi][ni], 0, 0, 0);
            __syncthreads();
        }
    }
#pragma unroll
    for (int ni = 0; ni < 4; ++ni) {
        const int col = bx * 128 + wn * 64 + ni * 16 + l16;
        const float bv = bias[col];
#pragma unroll
        for (int mi = 0; mi < 2; ++mi) {
            const int row0 = by * 64 + wm * 32 + mi * 16 + quad * 4;
#pragma unroll
            for (int rg = 0; rg < 4; ++rg)
                out[(size_t)(row0 + rg) * OUTF + col] = acc[mi][ni][rg] + bv;
        }
    }
}

extern "C" void kernel_launch(void* const* d_in, const int* in_sizes, int n_in,
                              void* d_out, int out_size, void* d_ws, size_t ws_size,
                              hipStream_t stream) {
    const float*    xx = (const float*)d_in[0];
    const uint32_t* qw = (const uint32_t*)d_in[1];
    const uint32_t* qz = (const uint32_t*)d_in[2];
    const float*    sc = (const float*)d_in[3];
    const float*    bs = (const float*)d_in[4];
    float* out = (float*)d_out;

    const size_t x16_bytes = (size_t)TOKENS * INF * sizeof(_Float16);  // 2 MB
    if (ws_size >= x16_bytes) {
        _Float16* x16 = (_Float16*)d_ws;
        prep<<<512 + (TOKENS * OUTF / 4) / NTH, NTH, 0, stream>>>(xx, x16, bs, out);
        qlin_main<<<(OUTF / 128) * (TOKENS / 64) * KSPLIT, NTH, 0, stream>>>(
            x16, qw, qz, sc, out);
    } else {
        dim3 grid(OUTF / 128, TOKENS / 64);
        qlin_fb<<<grid, NTH, 0, stream>>>(xx, qw, qz, sc, bs, out);
    }
}